// Round 10
// baseline (388.805 us; speedup 1.0000x reference)
//
#include <hip/hip_runtime.h>
#include <math.h>

#define SEQ 4096
#define DM  1024
#define NH  16
#define DH  64

typedef _Float16 h16;
typedef __attribute__((ext_vector_type(4))) _Float16 h16x4;
typedef __attribute__((ext_vector_type(8))) _Float16 h16x8;
typedef __attribute__((ext_vector_type(4))) float f32x4;

// async global->LDS, 16B per lane, dest = wave-uniform base + lane*16
__device__ __forceinline__ void gload_lds16(const h16* g, h16* l) {
    __builtin_amdgcn_global_load_lds(
        (const __attribute__((address_space(1))) void*)g,
        (__attribute__((address_space(3))) void*)l, 16, 0, 0);
}

// ---------------------------------------------------------------------------
// Single fused fp32 -> fp16 conversion for x + all 4 weights.
// ---------------------------------------------------------------------------
__global__ __launch_bounds__(256) void cvt_all(const float* __restrict__ x,
                                               const float* __restrict__ wq,
                                               const float* __restrict__ wk,
                                               const float* __restrict__ wv,
                                               const float* __restrict__ wo,
                                               h16* __restrict__ dst) {
    const size_t SD4 = (size_t)SEQ * DM / 4;   // 1M float4s
    const size_t DD4 = (size_t)DM * DM / 4;    // 256K float4s
    const size_t i = (size_t)blockIdx.x * 256 + threadIdx.x;
    const float* src;
    size_t off;
    if (i < SD4) { src = x; off = i; }
    else {
        const size_t j = i - SD4;
        const int wsel = (int)(j >> 18);       // DD4 = 2^18
        off = j & (DD4 - 1);
        src = (wsel == 0) ? wq : (wsel == 1) ? wk : (wsel == 2) ? wv : wo;
    }
    const float4 v = ((const float4*)src)[off];
    h16x4 o = { (h16)v.x, (h16)v.y, (h16)v.z, (h16)v.w };
    ((h16x4*)dst)[i] = o;
}

// ---------------------------------------------------------------------------
// m97-style MFMA GEMM: 128x128 tile, BK=64 (two 32-slabs), global_load_lds
// width-16 staging into unpadded GT=32 layout. 4 waves, 4x4 frags.
// ---------------------------------------------------------------------------
#define GT 32

// z = 0,1,2 -> Q (scaled), K, V^T outputs
__global__ __launch_bounds__(256) void gemm_qkv(const h16* __restrict__ xh,
                                                const h16* __restrict__ Wq,
                                                const h16* __restrict__ Wk,
                                                const h16* __restrict__ Wv,
                                                h16* __restrict__ Qh,
                                                h16* __restrict__ Kh,
                                                h16* __restrict__ Vth,
                                                float scl) {
    __shared__ h16 As[2][128 * GT];
    __shared__ h16 Bs[2][128 * GT];

    const int z    = blockIdx.z;
    const h16* B   = (z == 0) ? Wq : (z == 1) ? Wk : Wv;
    const int t    = threadIdx.x;
    const int lane = t & 63;
    const int w    = t >> 6;
    const int wm   = (w >> 1) * 64;
    const int wn   = (w & 1) * 64;
    const int l15  = lane & 15;
    const int lq   = lane >> 4;
    const int lq8  = lq * 8;
    const int m0   = blockIdx.y * 128;
    const int n0   = blockIdx.x * 128;
    const int K = DM, M = SEQ, N = DM;

    const int srow = w * 16 + (lane >> 2);
    const int scol = (lane & 3) * 8;
    const h16* pa0 = xh + (size_t)(m0 + srow) * K + scol;
    const h16* pa1 = xh + (size_t)(m0 + 64 + srow) * K + scol;
    const h16* pb0 = B  + (size_t)(n0 + srow) * K + scol;
    const h16* pb1 = B  + (size_t)(n0 + 64 + srow) * K + scol;

    f32x4 acc[4][4] = {};

    for (int k0 = 0; k0 < K; k0 += 64) {
        __syncthreads();
        #pragma unroll
        for (int s = 0; s < 2; ++s) {
            const int ko = k0 + s * 32;
            gload_lds16(pa0 + ko, &As[s][w * 512]);
            gload_lds16(pa1 + ko, &As[s][2048 + w * 512]);
            gload_lds16(pb0 + ko, &Bs[s][w * 512]);
            gload_lds16(pb1 + ko, &Bs[s][2048 + w * 512]);
        }
        __syncthreads();

        #pragma unroll
        for (int s = 0; s < 2; ++s) {
            h16x8 af[4], bf[4];
            #pragma unroll
            for (int i = 0; i < 4; ++i)
                af[i] = *(const h16x8*)&As[s][(wm + i * 16 + l15) * GT + lq8];
            #pragma unroll
            for (int j = 0; j < 4; ++j)
                bf[j] = *(const h16x8*)&Bs[s][(wn + j * 16 + l15) * GT + lq8];
            #pragma unroll
            for (int i = 0; i < 4; ++i)
                #pragma unroll
                for (int j = 0; j < 4; ++j)
                    acc[i][j] = __builtin_amdgcn_mfma_f32_16x16x32_f16(af[i], bf[j], acc[i][j], 0, 0, 0);
        }
    }

    const int cr = wm + lq * 4;
    const int cc = wn + l15;
    if (z == 2) {   // V^T: h16 [N][M], vectorized along M
        #pragma unroll
        for (int i = 0; i < 4; ++i)
            #pragma unroll
            for (int j = 0; j < 4; ++j) {
                const int gm0 = m0 + cr + i * 16;
                const int gn  = n0 + cc + j * 16;
                h16x4 v = { (h16)acc[i][j][0], (h16)acc[i][j][1],
                            (h16)acc[i][j][2], (h16)acc[i][j][3] };
                *(h16x4*)(Vth + (size_t)gn * M + gm0) = v;
            }
    } else {
        h16* Og = (z == 0) ? Qh : Kh;
        const float e = (z == 0) ? scl : 1.0f;
        #pragma unroll
        for (int i = 0; i < 4; ++i)
            #pragma unroll
            for (int j = 0; j < 4; ++j)
                #pragma unroll
                for (int r = 0; r < 4; ++r) {
                    const int gm = m0 + cr + i * 16 + r;
                    const int gn = n0 + cc + j * 16;
                    Og[(size_t)gm * N + gn] = (h16)(acc[i][j][r] * e);
                }
    }
}

// out[M][N] (f32) = AO (h16) @ Wo^T (h16). 64x128 tile -> grid 512 = 2/CU.
__global__ __launch_bounds__(256) void gemm_out(const h16* __restrict__ A,
                                                const h16* __restrict__ B,
                                                float* __restrict__ C) {
    __shared__ h16 As[2][64 * GT];
    __shared__ h16 Bs[2][128 * GT];

    const int t    = threadIdx.x;
    const int lane = t & 63;
    const int w    = t >> 6;
    const int wm   = (w >> 1) * 32;
    const int wn   = (w & 1) * 64;
    const int l15  = lane & 15;
    const int lq   = lane >> 4;
    const int lq8  = lq * 8;
    const int m0   = blockIdx.y * 64;
    const int n0   = blockIdx.x * 128;
    const int K = DM, N = DM;

    const int srow = w * 16 + (lane >> 2);
    const int scol = (lane & 3) * 8;
    const h16* pa0 = A + (size_t)(m0 + srow) * K + scol;
    const h16* pb0 = B + (size_t)(n0 + srow) * K + scol;
    const h16* pb1 = B + (size_t)(n0 + 64 + srow) * K + scol;

    f32x4 acc[2][4] = {};

    for (int k0 = 0; k0 < K; k0 += 64) {
        __syncthreads();
        #pragma unroll
        for (int s = 0; s < 2; ++s) {
            const int ko = k0 + s * 32;
            gload_lds16(pa0 + ko, &As[s][w * 512]);
            gload_lds16(pb0 + ko, &Bs[s][w * 512]);
            gload_lds16(pb1 + ko, &Bs[s][2048 + w * 512]);
        }
        __syncthreads();

        #pragma unroll
        for (int s = 0; s < 2; ++s) {
            h16x8 af[2], bf[4];
            #pragma unroll
            for (int i = 0; i < 2; ++i)
                af[i] = *(const h16x8*)&As[s][(wm + i * 16 + l15) * GT + lq8];
            #pragma unroll
            for (int j = 0; j < 4; ++j)
                bf[j] = *(const h16x8*)&Bs[s][(wn + j * 16 + l15) * GT + lq8];
            #pragma unroll
            for (int i = 0; i < 2; ++i)
                #pragma unroll
                for (int j = 0; j < 4; ++j)
                    acc[i][j] = __builtin_amdgcn_mfma_f32_16x16x32_f16(af[i], bf[j], acc[i][j], 0, 0, 0);
        }
    }

    const int cr = wm + lq * 4;
    const int cc = wn + l15;
    #pragma unroll
    for (int i = 0; i < 2; ++i)
        #pragma unroll
        for (int j = 0; j < 4; ++j)
            #pragma unroll
            for (int r = 0; r < 4; ++r)
                C[(size_t)(m0 + cr + i * 16 + r) * N + n0 + cc + j * 16] = acc[i][j][r];
}

// ---------------------------------------------------------------------------
// MFMA flash attention (causal), S^T formulation, exp2 domain,
// REGISTER-DIRECT K/V/Q: fragments loaded straight from global (L2-resident)
// into the MFMA operand layout (per-lane 16B contiguous) — no K/V LDS, no
// staging writes, NO BARRIERS in the k-loop. Only LDS use is the wave-local
// P^T round-trip (11.5 KB). kf/vf reload immediately after last use; the
// softmax chain (~400 cyc) hides L2 latency (~200 cyc).
// PST=72: P stores/reads 2-way max bank aliasing (free per m136).
// ---------------------------------------------------------------------------
#define PST 72

__global__ __launch_bounds__(256, 2) void flash_attn_mfma(
        const h16* __restrict__ Qg, const h16* __restrict__ Kg,
        const h16* __restrict__ Vt, h16* __restrict__ Og) {
    __shared__ h16 Ps[64 * PST];

    const int qt   = 63 - (int)blockIdx.y;   // heavy tiles dispatch first
    const int hh   = blockIdx.x;
    const int t    = threadIdx.x;
    const int lane = t & 63;
    const int w    = t >> 6;
    const int l15  = lane & 15;
    const int lq   = lane >> 4;
    const int lq8  = lq * 8;
    const int hc   = hh * DH;
    const int q0   = qt * 64;
    const int q_loc = w * 16 + l15;

    // Q fragments direct from global (B-operand layout, per-lane 16B)
    const h16* qp = Qg + (size_t)(q0 + q_loc) * DM + hc + lq8;
    h16x8 qf[2] = { *(const h16x8*)qp, *(const h16x8*)(qp + 32) };

    // K/V fragment base pointers (A-operand layout, per-lane 16B)
    const h16* kbase = Kg + (size_t)l15 * DM + hc + lq8;          // + (k0+jj*16)*DM + kc*32
    const h16* vbase = Vt + (size_t)(hc + l15) * SEQ + lq8;       // + jj*16*SEQ + k0 + kc*32

    h16x8 kf[2][4], vf[2][4];
    #pragma unroll
    for (int kc = 0; kc < 2; ++kc)
        #pragma unroll
        for (int jj = 0; jj < 4; ++jj) {
            kf[kc][jj] = *(const h16x8*)(kbase + (size_t)(jj * 16) * DM + kc * 32);
            vf[kc][jj] = *(const h16x8*)(vbase + (size_t)(jj * 16) * SEQ + kc * 32);
        }

    float m_st = -1e30f, l_st = 0.0f;
    f32x4 o[4] = {};
    h16* const ps = &Ps[(size_t)q_loc * PST];

    for (int kt = 0; kt <= qt; ++kt) {
        // ---- S^T = K Q^T (kf consumed; compiler waits vmcnt here) ----
        f32x4 s[4] = {};
        #pragma unroll
        for (int kc = 0; kc < 2; ++kc)
            #pragma unroll
            for (int jj = 0; jj < 4; ++jj)
                s[jj] = __builtin_amdgcn_mfma_f32_16x16x32_f16(kf[kc][jj], qf[kc], s[jj], 0, 0, 0);

        // prefetch next K frags (in flight during softmax + PV)
        if (kt < qt) {
            const int k0n = (kt + 1) * 64;
            #pragma unroll
            for (int kc = 0; kc < 2; ++kc)
                #pragma unroll
                for (int jj = 0; jj < 4; ++jj)
                    kf[kc][jj] = *(const h16x8*)(kbase + (size_t)(k0n + jj * 16) * DM + kc * 32);
        }

        // ---- online softmax: in-lane over 16 k + 2 shfls per reduction ----
        if (kt == qt) {   // block-uniform: diagonal tile only
            #pragma unroll
            for (int jj = 0; jj < 4; ++jj)
                #pragma unroll
                for (int r = 0; r < 4; ++r)
                    if ((jj * 16 + lq * 4 + r) > q_loc) s[jj][r] = -1e30f;
        }
        float mx = m_st;
        #pragma unroll
        for (int jj = 0; jj < 4; ++jj)
            #pragma unroll
            for (int r = 0; r < 4; ++r)
                mx = fmaxf(mx, s[jj][r]);
        mx = fmaxf(mx, __shfl_xor(mx, 16, 64));
        mx = fmaxf(mx, __shfl_xor(mx, 32, 64));
        const float alpha = exp2f(m_st - mx);
        m_st = mx;
        float sum = 0.0f;
        #pragma unroll
        for (int jj = 0; jj < 4; ++jj) {
            const float p0 = exp2f(s[jj][0] - mx);
            const float p1 = exp2f(s[jj][1] - mx);
            const float p2 = exp2f(s[jj][2] - mx);
            const float p3 = exp2f(s[jj][3] - mx);
            sum += (p0 + p1) + (p2 + p3);
            h16x4 pk = { (h16)p0, (h16)p1, (h16)p2, (h16)p3 };
            *(h16x4*)(ps + jj * 16 + lq * 4) = pk;
        }
        sum += __shfl_xor(sum, 16, 64);
        sum += __shfl_xor(sum, 32, 64);
        l_st = l_st * alpha + sum;
        #pragma unroll
        for (int jj = 0; jj < 4; ++jj)
            #pragma unroll
            for (int r = 0; r < 4; ++r)
                o[jj][r] *= alpha;

        // wave-local P^T round-trip (C-layout -> B-operand layout)
        asm volatile("s_waitcnt lgkmcnt(0)" ::: "memory");
        h16x8 pf[2];
        pf[0] = *(const h16x8*)(ps + lq8);
        pf[1] = *(const h16x8*)(ps + 32 + lq8);

        // ---- O^T += V^T P^T ----
        #pragma unroll
        for (int kc = 0; kc < 2; ++kc)
            #pragma unroll
            for (int jj = 0; jj < 4; ++jj)
                o[jj] = __builtin_amdgcn_mfma_f32_16x16x32_f16(vf[kc][jj], pf[kc], o[jj], 0, 0, 0);

        // prefetch next V frags (after last vf use)
        if (kt < qt) {
            const int k0n = (kt + 1) * 64;
            #pragma unroll
            for (int kc = 0; kc < 2; ++kc)
                #pragma unroll
                for (int jj = 0; jj < 4; ++jj)
                    vf[kc][jj] = *(const h16x8*)(vbase + (size_t)(jj * 16) * SEQ + k0n + kc * 32);
        }
    }

    // ---- epilogue: O = O^T / l ----
    const float il = 1.0f / l_st;
    const size_t qg = (size_t)(q0 + q_loc) * DM + hc;
    #pragma unroll
    for (int jj = 0; jj < 4; ++jj) {
        h16x4 ov = { (h16)(o[jj][0] * il), (h16)(o[jj][1] * il),
                     (h16)(o[jj][2] * il), (h16)(o[jj][3] * il) };
        *(h16x4*)(Og + qg + jj * 16 + lq * 4) = ov;
    }
}

// ---------------------------------------------------------------------------
extern "C" void kernel_launch(void* const* d_in, const int* in_sizes, int n_in,
                              void* d_out, int out_size, void* d_ws, size_t ws_size,
                              hipStream_t stream) {
    const float* x  = (const float*)d_in[0];
    const float* Wq = (const float*)d_in[1];
    const float* Wk = (const float*)d_in[2];
    const float* Wv = (const float*)d_in[3];
    const float* Wo = (const float*)d_in[4];
    float* out = (float*)d_out;

    const size_t SD = (size_t)SEQ * DM;   // 4M
    const size_t DD = (size_t)DM * DM;    // 1M

    h16* xh  = (h16*)d_ws;                // cvt_all relies on this contiguity
    h16* wqh = xh + SD;
    h16* wkh = wqh + DD;
    h16* wvh = wkh + DD;
    h16* woh = wvh + DD;
    h16* Qh  = woh + DD;
    h16* Kh  = Qh + SD;
    h16* Vth = Kh + SD;     // transposed: [DM][SEQ]
    h16* AOh = Vth + SD;

    const dim3 blk(256);

    cvt_all<<<(int)((SD + 4 * DD) / 4 / 256), blk, 0, stream>>>(x, Wq, Wk, Wv, Wo, xh);

    // Q pre-scaled by 1/sqrt(DH) * log2(e) for the exp2-domain softmax
    const float SCL = 0.125f * 1.44269504088896340736f;

    gemm_qkv<<<dim3(DM / 128, SEQ / 128, 3), blk, 0, stream>>>(
        xh, wqh, wkh, wvh, Qh, Kh, Vth, SCL);

    flash_attn_mfma<<<dim3(NH, 64), blk, 0, stream>>>(Qh, Kh, Vth, AOh);

    gemm_out<<<dim3(DM / 128, SEQ / 64), blk, 0, stream>>>(AOh, woh, out);
}

// Round 11
// 227.575 us; speedup vs baseline: 1.7085x; 1.7085x over previous
//
#include <hip/hip_runtime.h>
#include <math.h>

#define SEQ 4096
#define DM  1024
#define NH  16
#define DH  64

typedef _Float16 h16;
typedef __attribute__((ext_vector_type(4))) _Float16 h16x4;
typedef __attribute__((ext_vector_type(8))) _Float16 h16x8;
typedef __attribute__((ext_vector_type(4))) float f32x4;
typedef __attribute__((ext_vector_type(16))) float f32x16;

// async global->LDS, 16B per lane, dest = wave-uniform base + lane*16
__device__ __forceinline__ void gload_lds16(const h16* g, h16* l) {
    __builtin_amdgcn_global_load_lds(
        (const __attribute__((address_space(1))) void*)g,
        (__attribute__((address_space(3))) void*)l, 16, 0, 0);
}

// ---------------------------------------------------------------------------
// Single fused fp32 -> fp16 conversion for x + all 4 weights.
// ---------------------------------------------------------------------------
__global__ __launch_bounds__(256) void cvt_all(const float* __restrict__ x,
                                               const float* __restrict__ wq,
                                               const float* __restrict__ wk,
                                               const float* __restrict__ wv,
                                               const float* __restrict__ wo,
                                               h16* __restrict__ dst) {
    const size_t SD4 = (size_t)SEQ * DM / 4;   // 1M float4s
    const size_t DD4 = (size_t)DM * DM / 4;    // 256K float4s
    const size_t i = (size_t)blockIdx.x * 256 + threadIdx.x;
    const float* src;
    size_t off;
    if (i < SD4) { src = x; off = i; }
    else {
        const size_t j = i - SD4;
        const int wsel = (int)(j >> 18);       // DD4 = 2^18
        off = j & (DD4 - 1);
        src = (wsel == 0) ? wq : (wsel == 1) ? wk : (wsel == 2) ? wv : wo;
    }
    const float4 v = ((const float4*)src)[off];
    h16x4 o = { (h16)v.x, (h16)v.y, (h16)v.z, (h16)v.w };
    ((h16x4*)dst)[i] = o;
}

// ---------------------------------------------------------------------------
// m97-style MFMA GEMM: 128x128 tile, BK=64 (two 32-slabs), global_load_lds
// width-16 staging into unpadded GT=32 layout. 4 waves, 4x4 frags.
// ---------------------------------------------------------------------------
#define GT 32

// z = 0,1,2 -> Q (scaled), K, V^T outputs
__global__ __launch_bounds__(256) void gemm_qkv(const h16* __restrict__ xh,
                                                const h16* __restrict__ Wq,
                                                const h16* __restrict__ Wk,
                                                const h16* __restrict__ Wv,
                                                h16* __restrict__ Qh,
                                                h16* __restrict__ Kh,
                                                h16* __restrict__ Vth,
                                                float scl) {
    __shared__ h16 As[2][128 * GT];
    __shared__ h16 Bs[2][128 * GT];

    const int z    = blockIdx.z;
    const h16* B   = (z == 0) ? Wq : (z == 1) ? Wk : Wv;
    const int t    = threadIdx.x;
    const int lane = t & 63;
    const int w    = t >> 6;
    const int wm   = (w >> 1) * 64;
    const int wn   = (w & 1) * 64;
    const int l15  = lane & 15;
    const int lq   = lane >> 4;
    const int lq8  = lq * 8;
    const int m0   = blockIdx.y * 128;
    const int n0   = blockIdx.x * 128;
    const int K = DM, M = SEQ, N = DM;

    const int srow = w * 16 + (lane >> 2);
    const int scol = (lane & 3) * 8;
    const h16* pa0 = xh + (size_t)(m0 + srow) * K + scol;
    const h16* pa1 = xh + (size_t)(m0 + 64 + srow) * K + scol;
    const h16* pb0 = B  + (size_t)(n0 + srow) * K + scol;
    const h16* pb1 = B  + (size_t)(n0 + 64 + srow) * K + scol;

    f32x4 acc[4][4] = {};

    for (int k0 = 0; k0 < K; k0 += 64) {
        __syncthreads();
        #pragma unroll
        for (int s = 0; s < 2; ++s) {
            const int ko = k0 + s * 32;
            gload_lds16(pa0 + ko, &As[s][w * 512]);
            gload_lds16(pa1 + ko, &As[s][2048 + w * 512]);
            gload_lds16(pb0 + ko, &Bs[s][w * 512]);
            gload_lds16(pb1 + ko, &Bs[s][2048 + w * 512]);
        }
        __syncthreads();

        #pragma unroll
        for (int s = 0; s < 2; ++s) {
            h16x8 af[4], bf[4];
            #pragma unroll
            for (int i = 0; i < 4; ++i)
                af[i] = *(const h16x8*)&As[s][(wm + i * 16 + l15) * GT + lq8];
            #pragma unroll
            for (int j = 0; j < 4; ++j)
                bf[j] = *(const h16x8*)&Bs[s][(wn + j * 16 + l15) * GT + lq8];
            #pragma unroll
            for (int i = 0; i < 4; ++i)
                #pragma unroll
                for (int j = 0; j < 4; ++j)
                    acc[i][j] = __builtin_amdgcn_mfma_f32_16x16x32_f16(af[i], bf[j], acc[i][j], 0, 0, 0);
        }
    }

    const int cr = wm + lq * 4;
    const int cc = wn + l15;
    if (z == 2) {   // V^T: h16 [N][M], vectorized along M
        #pragma unroll
        for (int i = 0; i < 4; ++i)
            #pragma unroll
            for (int j = 0; j < 4; ++j) {
                const int gm0 = m0 + cr + i * 16;
                const int gn  = n0 + cc + j * 16;
                h16x4 v = { (h16)acc[i][j][0], (h16)acc[i][j][1],
                            (h16)acc[i][j][2], (h16)acc[i][j][3] };
                *(h16x4*)(Vth + (size_t)gn * M + gm0) = v;
            }
    } else {
        h16* Og = (z == 0) ? Qh : Kh;
        const float e = (z == 0) ? scl : 1.0f;
        #pragma unroll
        for (int i = 0; i < 4; ++i)
            #pragma unroll
            for (int j = 0; j < 4; ++j)
                #pragma unroll
                for (int r = 0; r < 4; ++r) {
                    const int gm = m0 + cr + i * 16 + r;
                    const int gn = n0 + cc + j * 16;
                    Og[(size_t)gm * N + gn] = (h16)(acc[i][j][r] * e);
                }
    }
}

// out[M][N] (f32) = AO (h16) @ Wo^T (h16). 64x128 tile -> grid 512 = 2/CU.
__global__ __launch_bounds__(256) void gemm_out(const h16* __restrict__ A,
                                                const h16* __restrict__ B,
                                                float* __restrict__ C) {
    __shared__ h16 As[2][64 * GT];
    __shared__ h16 Bs[2][128 * GT];

    const int t    = threadIdx.x;
    const int lane = t & 63;
    const int w    = t >> 6;
    const int wm   = (w >> 1) * 32;
    const int wn   = (w & 1) * 64;
    const int l15  = lane & 15;
    const int lq   = lane >> 4;
    const int lq8  = lq * 8;
    const int m0   = blockIdx.y * 64;
    const int n0   = blockIdx.x * 128;
    const int K = DM, N = DM;

    const int srow = w * 16 + (lane >> 2);
    const int scol = (lane & 3) * 8;
    const h16* pa0 = A + (size_t)(m0 + srow) * K + scol;
    const h16* pb0 = B + (size_t)(n0 + srow) * K + scol;
    const h16* pb1 = B + (size_t)(n0 + 64 + srow) * K + scol;

    f32x4 acc[2][4] = {};

    for (int k0 = 0; k0 < K; k0 += 64) {
        __syncthreads();
        #pragma unroll
        for (int s = 0; s < 2; ++s) {
            const int ko = k0 + s * 32;
            gload_lds16(pa0 + ko, &As[s][w * 512]);
            gload_lds16(pb0 + ko, &Bs[s][w * 512]);
            gload_lds16(pb1 + ko, &Bs[s][2048 + w * 512]);
        }
        __syncthreads();

        #pragma unroll
        for (int s = 0; s < 2; ++s) {
            h16x8 af[2], bf[4];
            #pragma unroll
            for (int i = 0; i < 2; ++i)
                af[i] = *(const h16x8*)&As[s][(wm + i * 16 + l15) * GT + lq8];
            #pragma unroll
            for (int j = 0; j < 4; ++j)
                bf[j] = *(const h16x8*)&Bs[s][(wn + j * 16 + l15) * GT + lq8];
            #pragma unroll
            for (int i = 0; i < 2; ++i)
                #pragma unroll
                for (int j = 0; j < 4; ++j)
                    acc[i][j] = __builtin_amdgcn_mfma_f32_16x16x32_f16(af[i], bf[j], acc[i][j], 0, 0, 0);
        }
    }

    const int cr = wm + lq * 4;
    const int cc = wn + l15;
    #pragma unroll
    for (int i = 0; i < 2; ++i)
        #pragma unroll
        for (int j = 0; j < 4; ++j)
            #pragma unroll
            for (int r = 0; r < 4; ++r)
                C[(size_t)(m0 + cr + i * 16 + r) * N + n0 + cc + j * 16] = acc[i][j][r];
}

// ---------------------------------------------------------------------------
// MFMA flash attention (causal), S^T formulation, exp2 domain, 32x32x16 MFMA.
// Block = (128-q tile, head), grid (NH, 32) = 512 blocks. Wave w owns 32 q
// (one q per lane pair-half): K/V LDS traffic per q HALVES vs the 16x16
// version, softmax reduction needs only ONE shfl (in-lane 32 + xor-32).
// 32x32x16 layouts: A m=lane&31, k=(lane>>5)*8+j (analogy of verified 16x16);
// C/D col=lane&31, row=(reg&3)+8*(reg>>2)+4*(lane>>5) [m74/m101].
// Heavy/light q-tile pairing via index map -> every CU gets ~66 iters.
// KST=72: row stride 36 dw == 4 (mod 32): 8-lane phases hit disjoint bank
// quads -> predicted conflict-free. LDS 36 KB.
// ---------------------------------------------------------------------------
#define KST 72

__global__ __launch_bounds__(256, 2) void flash_attn_mfma(
        const h16* __restrict__ Qg, const h16* __restrict__ Kg,
        const h16* __restrict__ Vt, h16* __restrict__ Og) {
    __shared__ h16 Ks[64 * KST];        // [k_local][d]
    __shared__ h16 Vs[64 * KST];        // [d][k_local]
    __shared__ h16 Ps[4 * 32 * KST];    // per-wave [q_local 32][k 64]

    const int yb   = blockIdx.y;
    const int qb   = (yb < 16) ? (31 - yb) : (yb - 16);   // pair heavy+light
    const int hh   = blockIdx.x;
    const int t    = threadIdx.x;
    const int lane = t & 63;
    const int w    = t >> 6;
    const int l31  = lane & 31;
    const int half = lane >> 5;
    const int h8   = half * 8;
    const int hc   = hh * DH;
    const int q0   = qb * 128;
    const int qg   = q0 + w * 32 + l31;      // this lane's q (C-layout column)

    const int r1 = t >> 3;               // 0..31
    const int r2 = r1 + 32;
    const int c1 = (t & 7) * 8;

    // Q fragments direct from global (B-operand layout; one-time scatter)
    const h16* qp = Qg + (size_t)qg * DM + hc + h8;
    h16x8 qf[4];
    #pragma unroll
    for (int ds = 0; ds < 4; ++ds) qf[ds] = *(const h16x8*)(qp + ds * 16);

    // preload kt=0 K/V tile into regs
    h16x8 kv1 = *(const h16x8*)(Kg + (size_t)(r1) * DM + hc + c1);
    h16x8 kv2 = *(const h16x8*)(Kg + (size_t)(r2) * DM + hc + c1);
    h16x8 vv1 = *(const h16x8*)(Vt + (size_t)(hc + r1) * SEQ + c1);
    h16x8 vv2 = *(const h16x8*)(Vt + (size_t)(hc + r2) * SEQ + c1);

    float m_st = -1e30f, l_st = 0.0f;
    f32x16 o[2] = {};
    h16* const pw = &Ps[(size_t)(w * 32 + l31) * KST];

    const int ktmax = 2 * qb + 1;
    for (int kt = 0; kt <= ktmax; ++kt) {
        __syncthreads();   // prior iter's frag reads drained
        *(h16x8*)&Ks[r1 * KST + c1] = kv1;
        *(h16x8*)&Ks[r2 * KST + c1] = kv2;
        *(h16x8*)&Vs[r1 * KST + c1] = vv1;
        *(h16x8*)&Vs[r2 * KST + c1] = vv2;
        __syncthreads();
        if (kt < ktmax) {   // prefetch next K/V tile (overlaps compute)
            const int k0n = (kt + 1) * 64;
            kv1 = *(const h16x8*)(Kg + (size_t)(k0n + r1) * DM + hc + c1);
            kv2 = *(const h16x8*)(Kg + (size_t)(k0n + r2) * DM + hc + c1);
            vv1 = *(const h16x8*)(Vt + (size_t)(hc + r1) * SEQ + k0n + c1);
            vv2 = *(const h16x8*)(Vt + (size_t)(hc + r2) * SEQ + k0n + c1);
        }

        // ---- S^T = K Q^T: s[kb] covers k rows kb*32..+32, q = lane cols ----
        f32x16 s[2] = {};
        #pragma unroll
        for (int ds = 0; ds < 4; ++ds) {
            const h16x8 kf0 = *(const h16x8*)&Ks[(l31) * KST + ds * 16 + h8];
            const h16x8 kf1 = *(const h16x8*)&Ks[(32 + l31) * KST + ds * 16 + h8];
            s[0] = __builtin_amdgcn_mfma_f32_32x32x16_f16(kf0, qf[ds], s[0], 0, 0, 0);
            s[1] = __builtin_amdgcn_mfma_f32_32x32x16_f16(kf1, qf[ds], s[1], 0, 0, 0);
        }

        // ---- causal mask (only the last two k-tiles straddle the diag) ----
        if (kt >= 2 * qb) {
            #pragma unroll
            for (int kb = 0; kb < 2; ++kb)
                #pragma unroll
                for (int rg = 0; rg < 16; ++rg) {
                    const int k_glob = kt * 64 + kb * 32 + (rg & 3) + 8 * (rg >> 2) + 4 * half;
                    if (k_glob > qg) s[kb][rg] = -1e30f;
                }
        }

        // ---- online softmax: 32 in-lane + ONE shfl per reduction ----
        float mx = m_st;
        #pragma unroll
        for (int kb = 0; kb < 2; ++kb)
            #pragma unroll
            for (int rg = 0; rg < 16; ++rg)
                mx = fmaxf(mx, s[kb][rg]);
        mx = fmaxf(mx, __shfl_xor(mx, 32, 64));
        const float alpha = exp2f(m_st - mx);
        m_st = mx;
        float sum = 0.0f;
        #pragma unroll
        for (int kb = 0; kb < 2; ++kb)
            #pragma unroll
            for (int rg = 0; rg < 4; ++rg) {
                const float p0 = exp2f(s[kb][rg * 4 + 0] - mx);
                const float p1 = exp2f(s[kb][rg * 4 + 1] - mx);
                const float p2 = exp2f(s[kb][rg * 4 + 2] - mx);
                const float p3 = exp2f(s[kb][rg * 4 + 3] - mx);
                sum += (p0 + p1) + (p2 + p3);
                h16x4 pk = { (h16)p0, (h16)p1, (h16)p2, (h16)p3 };
                *(h16x4*)(pw + kb * 32 + rg * 8 + 4 * half) = pk;   // [q][k] layout
            }
        sum += __shfl_xor(sum, 32, 64);
        l_st = l_st * alpha + sum;
        #pragma unroll
        for (int db = 0; db < 2; ++db)
            #pragma unroll
            for (int rg = 0; rg < 16; ++rg)
                o[db][rg] *= alpha;

        // wave-local P round-trip: C-layout -> B-operand layout
        asm volatile("s_waitcnt lgkmcnt(0)" ::: "memory");
        h16x8 pf[4];
        #pragma unroll
        for (int ks = 0; ks < 4; ++ks)
            pf[ks] = *(const h16x8*)(pw + ks * 16 + h8);

        // ---- O^T += V^T P^T : o[db] covers d rows db*32..+32 ----
        #pragma unroll
        for (int ks = 0; ks < 4; ++ks) {
            const h16x8 vf0 = *(const h16x8*)&Vs[(l31) * KST + ks * 16 + h8];
            const h16x8 vf1 = *(const h16x8*)&Vs[(32 + l31) * KST + ks * 16 + h8];
            o[0] = __builtin_amdgcn_mfma_f32_32x32x16_f16(vf0, pf[ks], o[0], 0, 0, 0);
            o[1] = __builtin_amdgcn_mfma_f32_32x32x16_f16(vf1, pf[ks], o[1], 0, 0, 0);
        }
    }

    // ---- epilogue: O = O^T / l (d = C-layout row, q = col) ----
    const float il = 1.0f / l_st;
    const size_t qrow = (size_t)qg * DM + hc;
    #pragma unroll
    for (int db = 0; db < 2; ++db)
        #pragma unroll
        for (int rg = 0; rg < 4; ++rg) {
            const int d = db * 32 + rg * 8 + 4 * half;
            h16x4 ov = { (h16)(o[db][rg * 4 + 0] * il), (h16)(o[db][rg * 4 + 1] * il),
                         (h16)(o[db][rg * 4 + 2] * il), (h16)(o[db][rg * 4 + 3] * il) };
            *(h16x4*)(Og + qrow + d) = ov;
        }
}

// ---------------------------------------------------------------------------
extern "C" void kernel_launch(void* const* d_in, const int* in_sizes, int n_in,
                              void* d_out, int out_size, void* d_ws, size_t ws_size,
                              hipStream_t stream) {
    const float* x  = (const float*)d_in[0];
    const float* Wq = (const float*)d_in[1];
    const float* Wk = (const float*)d_in[2];
    const float* Wv = (const float*)d_in[3];
    const float* Wo = (const float*)d_in[4];
    float* out = (float*)d_out;

    const size_t SD = (size_t)SEQ * DM;   // 4M
    const size_t DD = (size_t)DM * DM;    // 1M

    h16* xh  = (h16*)d_ws;                // cvt_all relies on this contiguity
    h16* wqh = xh + SD;
    h16* wkh = wqh + DD;
    h16* wvh = wkh + DD;
    h16* woh = wvh + DD;
    h16* Qh  = woh + DD;
    h16* Kh  = Qh + SD;
    h16* Vth = Kh + SD;     // transposed: [DM][SEQ]
    h16* AOh = Vth + SD;

    const dim3 blk(256);

    cvt_all<<<(int)((SD + 4 * DD) / 4 / 256), blk, 0, stream>>>(x, Wq, Wk, Wv, Wo, xh);

    // Q pre-scaled by 1/sqrt(DH) * log2(e) for the exp2-domain softmax
    const float SCL = 0.125f * 1.44269504088896340736f;

    gemm_qkv<<<dim3(DM / 128, SEQ / 128, 3), blk, 0, stream>>>(
        xh, wqh, wkh, wvh, Qh, Kh, Vth, SCL);

    flash_attn_mfma<<<dim3(NH, 32), blk, 0, stream>>>(Qh, Kh, Vth, AOh);

    gemm_out<<<dim3(DM / 128, SEQ / 64), blk, 0, stream>>>(AOh, woh, out);
}

// Round 12
// 223.930 us; speedup vs baseline: 1.7363x; 1.0163x over previous
//
#include <hip/hip_runtime.h>
#include <math.h>

#define SEQ 4096
#define DM  1024
#define NH  16
#define DH  64
#define NS  4      // k-splits per q-tile

typedef _Float16 h16;
typedef __attribute__((ext_vector_type(4))) _Float16 h16x4;
typedef __attribute__((ext_vector_type(8))) _Float16 h16x8;
typedef __attribute__((ext_vector_type(4))) float f32x4;

// async global->LDS, 16B per lane, dest = wave-uniform base + lane*16
__device__ __forceinline__ void gload_lds16(const h16* g, h16* l) {
    __builtin_amdgcn_global_load_lds(
        (const __attribute__((address_space(1))) void*)g,
        (__attribute__((address_space(3))) void*)l, 16, 0, 0);
}

// ---------------------------------------------------------------------------
// Single fused fp32 -> fp16 conversion for x + all 4 weights.
// ---------------------------------------------------------------------------
__global__ __launch_bounds__(256) void cvt_all(const float* __restrict__ x,
                                               const float* __restrict__ wq,
                                               const float* __restrict__ wk,
                                               const float* __restrict__ wv,
                                               const float* __restrict__ wo,
                                               h16* __restrict__ dst) {
    const size_t SD4 = (size_t)SEQ * DM / 4;   // 1M float4s
    const size_t DD4 = (size_t)DM * DM / 4;    // 256K float4s
    const size_t i = (size_t)blockIdx.x * 256 + threadIdx.x;
    const float* src;
    size_t off;
    if (i < SD4) { src = x; off = i; }
    else {
        const size_t j = i - SD4;
        const int wsel = (int)(j >> 18);       // DD4 = 2^18
        off = j & (DD4 - 1);
        src = (wsel == 0) ? wq : (wsel == 1) ? wk : (wsel == 2) ? wv : wo;
    }
    const float4 v = ((const float4*)src)[off];
    h16x4 o = { (h16)v.x, (h16)v.y, (h16)v.z, (h16)v.w };
    ((h16x4*)dst)[i] = o;
}

// ---------------------------------------------------------------------------
// m97-style MFMA GEMM: 128x128 tile, BK=64 (two 32-slabs), global_load_lds
// width-16 staging into unpadded GT=32 layout. 4 waves, 4x4 frags.
// ---------------------------------------------------------------------------
#define GT 32

// z = 0,1,2 -> Q (scaled), K, V^T outputs
__global__ __launch_bounds__(256) void gemm_qkv(const h16* __restrict__ xh,
                                                const h16* __restrict__ Wq,
                                                const h16* __restrict__ Wk,
                                                const h16* __restrict__ Wv,
                                                h16* __restrict__ Qh,
                                                h16* __restrict__ Kh,
                                                h16* __restrict__ Vth,
                                                float scl) {
    __shared__ h16 As[2][128 * GT];
    __shared__ h16 Bs[2][128 * GT];

    const int z    = blockIdx.z;
    const h16* B   = (z == 0) ? Wq : (z == 1) ? Wk : Wv;
    const int t    = threadIdx.x;
    const int lane = t & 63;
    const int w    = t >> 6;
    const int wm   = (w >> 1) * 64;
    const int wn   = (w & 1) * 64;
    const int l15  = lane & 15;
    const int lq   = lane >> 4;
    const int lq8  = lq * 8;
    const int m0   = blockIdx.y * 128;
    const int n0   = blockIdx.x * 128;
    const int K = DM, M = SEQ, N = DM;

    const int srow = w * 16 + (lane >> 2);
    const int scol = (lane & 3) * 8;
    const h16* pa0 = xh + (size_t)(m0 + srow) * K + scol;
    const h16* pa1 = xh + (size_t)(m0 + 64 + srow) * K + scol;
    const h16* pb0 = B  + (size_t)(n0 + srow) * K + scol;
    const h16* pb1 = B  + (size_t)(n0 + 64 + srow) * K + scol;

    f32x4 acc[4][4] = {};

    for (int k0 = 0; k0 < K; k0 += 64) {
        __syncthreads();
        #pragma unroll
        for (int s = 0; s < 2; ++s) {
            const int ko = k0 + s * 32;
            gload_lds16(pa0 + ko, &As[s][w * 512]);
            gload_lds16(pa1 + ko, &As[s][2048 + w * 512]);
            gload_lds16(pb0 + ko, &Bs[s][w * 512]);
            gload_lds16(pb1 + ko, &Bs[s][2048 + w * 512]);
        }
        __syncthreads();

        #pragma unroll
        for (int s = 0; s < 2; ++s) {
            h16x8 af[4], bf[4];
            #pragma unroll
            for (int i = 0; i < 4; ++i)
                af[i] = *(const h16x8*)&As[s][(wm + i * 16 + l15) * GT + lq8];
            #pragma unroll
            for (int j = 0; j < 4; ++j)
                bf[j] = *(const h16x8*)&Bs[s][(wn + j * 16 + l15) * GT + lq8];
            #pragma unroll
            for (int i = 0; i < 4; ++i)
                #pragma unroll
                for (int j = 0; j < 4; ++j)
                    acc[i][j] = __builtin_amdgcn_mfma_f32_16x16x32_f16(af[i], bf[j], acc[i][j], 0, 0, 0);
        }
    }

    const int cr = wm + lq * 4;
    const int cc = wn + l15;
    if (z == 2) {   // V^T: h16 [N][M], vectorized along M
        #pragma unroll
        for (int i = 0; i < 4; ++i)
            #pragma unroll
            for (int j = 0; j < 4; ++j) {
                const int gm0 = m0 + cr + i * 16;
                const int gn  = n0 + cc + j * 16;
                h16x4 v = { (h16)acc[i][j][0], (h16)acc[i][j][1],
                            (h16)acc[i][j][2], (h16)acc[i][j][3] };
                *(h16x4*)(Vth + (size_t)gn * M + gm0) = v;
            }
    } else {
        h16* Og = (z == 0) ? Qh : Kh;
        const float e = (z == 0) ? scl : 1.0f;
        #pragma unroll
        for (int i = 0; i < 4; ++i)
            #pragma unroll
            for (int j = 0; j < 4; ++j)
                #pragma unroll
                for (int r = 0; r < 4; ++r) {
                    const int gm = m0 + cr + i * 16 + r;
                    const int gn = n0 + cc + j * 16;
                    Og[(size_t)gm * N + gn] = (h16)(acc[i][j][r] * e);
                }
    }
}

// out[M][N] (f32) = AO (h16) @ Wo^T (h16). 64x128 tile -> grid 512 = 2/CU.
__global__ __launch_bounds__(256) void gemm_out(const h16* __restrict__ A,
                                                const h16* __restrict__ B,
                                                float* __restrict__ C) {
    __shared__ h16 As[2][64 * GT];
    __shared__ h16 Bs[2][128 * GT];

    const int t    = threadIdx.x;
    const int lane = t & 63;
    const int w    = t >> 6;
    const int wm   = (w >> 1) * 32;
    const int wn   = (w & 1) * 64;
    const int l15  = lane & 15;
    const int lq   = lane >> 4;
    const int lq8  = lq * 8;
    const int m0   = blockIdx.y * 64;
    const int n0   = blockIdx.x * 128;
    const int K = DM, N = DM;

    const int srow = w * 16 + (lane >> 2);
    const int scol = (lane & 3) * 8;
    const h16* pa0 = A + (size_t)(m0 + srow) * K + scol;
    const h16* pb0 = B + (size_t)(n0 + srow) * K + scol;
    const h16* pb1 = B + (size_t)(n0 + 64 + srow) * K + scol;

    f32x4 acc[2][4] = {};

    for (int k0 = 0; k0 < K; k0 += 64) {
        __syncthreads();
        #pragma unroll
        for (int s = 0; s < 2; ++s) {
            const int ko = k0 + s * 32;
            gload_lds16(pa0 + ko, &As[s][w * 512]);
            gload_lds16(pb0 + ko, &Bs[s][w * 512]);
            gload_lds16(pb1 + ko, &Bs[s][2048 + w * 512]);
        }
        __syncthreads();

        #pragma unroll
        for (int s = 0; s < 2; ++s) {
            h16x8 af[2], bf[4];
            #pragma unroll
            for (int i = 0; i < 2; ++i)
                af[i] = *(const h16x8*)&As[s][(wm + i * 16 + l15) * GT + lq8];
            #pragma unroll
            for (int j = 0; j < 4; ++j)
                bf[j] = *(const h16x8*)&Bs[s][(wn + j * 16 + l15) * GT + lq8];
            #pragma unroll
            for (int i = 0; i < 2; ++i)
                #pragma unroll
                for (int j = 0; j < 4; ++j)
                    acc[i][j] = __builtin_amdgcn_mfma_f32_16x16x32_f16(af[i], bf[j], acc[i][j], 0, 0, 0);
        }
    }

    const int cr = wm + lq * 4;
    const int cc = wn + l15;
    #pragma unroll
    for (int i = 0; i < 2; ++i)
        #pragma unroll
        for (int j = 0; j < 4; ++j)
            #pragma unroll
            for (int r = 0; r < 4; ++r)
                C[(size_t)(m0 + cr + i * 16 + r) * N + n0 + cc + j * 16] = acc[i][j][r];
}

// ---------------------------------------------------------------------------
// SPLIT-K MFMA flash attention (causal), S^T formulation, exp2 domain.
// Grid (NH, 64, NS): block = (head, 64-q tile, k-split). Each block walks
// only its chunk = ceil((qt+1)/NS) k-tiles (max 16 serial iterations, 4x
// shorter chains than the monolithic version) and writes UNNORMALIZED
// partial O (h16) + per-row (m,l) (f32). 4096 blocks = 16/CU queued ->
// latency chains overlap across independent blocks. combine() merges.
// ---------------------------------------------------------------------------
#define AST 80

__global__ __launch_bounds__(256, 3) void flash_attn_split(
        const h16* __restrict__ Qg, const h16* __restrict__ Kg,
        const h16* __restrict__ Vt, h16* __restrict__ OP,
        float* __restrict__ Mb, float* __restrict__ Lb) {
    __shared__ h16 Ks[64 * AST];   // [k_local][d]
    __shared__ h16 Vs[64 * AST];   // [d][k_local]
    __shared__ h16 Ps[64 * AST];   // [q][k]

    const int qt   = 63 - (int)blockIdx.y;   // big chunks dispatch first
    const int hh   = blockIdx.x;
    const int sp   = blockIdx.z;
    const int t    = threadIdx.x;
    const int lane = t & 63;
    const int w    = t >> 6;
    const int l15  = lane & 15;
    const int lq   = lane >> 4;
    const int lq8  = lq * 8;
    const int hc   = hh * DH;
    const int q0   = qt * 64;
    const int q_loc = w * 16 + l15;

    const int ntile = qt + 1;
    const int chunk = (ntile + NS - 1) / NS;
    const int kts   = sp * chunk;
    const int kte   = (kts + chunk < ntile) ? (kts + chunk) : ntile;

    const int r1 = t >> 3;             // 0..31
    const int r2 = r1 + 32;
    const int c1 = (t & 7) * 8;

    // stage Q into Ks (consumed into regs before loop overwrites)
    *(h16x8*)&Ks[r1 * AST + c1] = *(const h16x8*)(Qg + (size_t)(q0 + r1) * DM + hc + c1);
    *(h16x8*)&Ks[r2 * AST + c1] = *(const h16x8*)(Qg + (size_t)(q0 + r2) * DM + hc + c1);

    // preload first K/V tile of this split (kts <= 48 always: in-bounds)
    const int kb0 = kts * 64;
    h16x8 kv1 = *(const h16x8*)(Kg + (size_t)(kb0 + r1) * DM + hc + c1);
    h16x8 kv2 = *(const h16x8*)(Kg + (size_t)(kb0 + r2) * DM + hc + c1);
    h16x8 vv1 = *(const h16x8*)(Vt + (size_t)(hc + r1) * SEQ + kb0 + c1);
    h16x8 vv2 = *(const h16x8*)(Vt + (size_t)(hc + r2) * SEQ + kb0 + c1);

    __syncthreads();
    h16x8 qf[2];
    qf[0] = *(const h16x8*)&Ks[q_loc * AST + lq8];
    qf[1] = *(const h16x8*)&Ks[q_loc * AST + 32 + lq8];

    float m_st = -1e30f, l_st = 0.0f;
    f32x4 o[4] = {};
    h16* const ps = &Ps[(size_t)q_loc * AST];

    for (int kt = kts; kt < kte; ++kt) {
        __syncthreads();   // prior frag/qf reads drained
        *(h16x8*)&Ks[r1 * AST + c1] = kv1;
        *(h16x8*)&Ks[r2 * AST + c1] = kv2;
        *(h16x8*)&Vs[r1 * AST + c1] = vv1;
        *(h16x8*)&Vs[r2 * AST + c1] = vv2;
        __syncthreads();
        if (kt + 1 < kte) {   // prefetch next K/V tile (overlaps compute)
            const int k0n = (kt + 1) * 64;
            kv1 = *(const h16x8*)(Kg + (size_t)(k0n + r1) * DM + hc + c1);
            kv2 = *(const h16x8*)(Kg + (size_t)(k0n + r2) * DM + hc + c1);
            vv1 = *(const h16x8*)(Vt + (size_t)(hc + r1) * SEQ + k0n + c1);
            vv2 = *(const h16x8*)(Vt + (size_t)(hc + r2) * SEQ + k0n + c1);
        }

        // ---- S^T = K Q^T (one q per lane in C-layout cols) ----
        f32x4 s[4] = {};
        #pragma unroll
        for (int kc = 0; kc < 2; ++kc)
            #pragma unroll
            for (int jj = 0; jj < 4; ++jj) {
                const h16x8 kf = *(const h16x8*)&Ks[(jj * 16 + l15) * AST + kc * 32 + lq8];
                s[jj] = __builtin_amdgcn_mfma_f32_16x16x32_f16(kf, qf[kc], s[jj], 0, 0, 0);
            }

        // ---- online softmax: in-lane over 16 k + 2 shfls ----
        if (kt == qt) {   // diagonal tile (only last split reaches it)
            #pragma unroll
            for (int jj = 0; jj < 4; ++jj)
                #pragma unroll
                for (int r = 0; r < 4; ++r)
                    if ((jj * 16 + lq * 4 + r) > q_loc) s[jj][r] = -1e30f;
        }
        float mx = m_st;
        #pragma unroll
        for (int jj = 0; jj < 4; ++jj)
            #pragma unroll
            for (int r = 0; r < 4; ++r)
                mx = fmaxf(mx, s[jj][r]);
        mx = fmaxf(mx, __shfl_xor(mx, 16, 64));
        mx = fmaxf(mx, __shfl_xor(mx, 32, 64));
        const float alpha = exp2f(m_st - mx);
        m_st = mx;
        float sum = 0.0f;
        #pragma unroll
        for (int jj = 0; jj < 4; ++jj) {
            const float p0 = exp2f(s[jj][0] - mx);
            const float p1 = exp2f(s[jj][1] - mx);
            const float p2 = exp2f(s[jj][2] - mx);
            const float p3 = exp2f(s[jj][3] - mx);
            sum += (p0 + p1) + (p2 + p3);
            h16x4 pk = { (h16)p0, (h16)p1, (h16)p2, (h16)p3 };
            *(h16x4*)(ps + jj * 16 + lq * 4) = pk;
        }
        sum += __shfl_xor(sum, 16, 64);
        sum += __shfl_xor(sum, 32, 64);
        l_st = l_st * alpha + sum;
        #pragma unroll
        for (int jj = 0; jj < 4; ++jj)
            #pragma unroll
            for (int r = 0; r < 4; ++r)
                o[jj][r] *= alpha;

        // wave-local P^T round-trip (own 16-row band only)
        asm volatile("s_waitcnt lgkmcnt(0)" ::: "memory");
        h16x8 pf[2];
        pf[0] = *(const h16x8*)(ps + lq8);
        pf[1] = *(const h16x8*)(ps + 32 + lq8);

        // ---- O^T += V^T P^T ----
        #pragma unroll
        for (int kc = 0; kc < 2; ++kc)
            #pragma unroll
            for (int jj = 0; jj < 4; ++jj) {
                const h16x8 vf = *(const h16x8*)&Vs[(jj * 16 + l15) * AST + kc * 32 + lq8];
                o[jj] = __builtin_amdgcn_mfma_f32_16x16x32_f16(vf, pf[kc], o[jj], 0, 0, 0);
            }
    }

    // ---- epilogue: write UNNORMALIZED partial O + (m, l) ----
    h16* const op = OP + (size_t)sp * SEQ * DM;
    const size_t qg = (size_t)(q0 + q_loc) * DM + hc;
    #pragma unroll
    for (int jj = 0; jj < 4; ++jj) {
        h16x4 ov = { (h16)o[jj][0], (h16)o[jj][1], (h16)o[jj][2], (h16)o[jj][3] };
        *(h16x4*)(op + qg + jj * 16 + lq * 4) = ov;
    }
    if (lq == 0) {   // one lane per q-row (all lq agree after xor16/32)
        const size_t mi = ((size_t)sp * NH + hh) * SEQ + q0 + q_loc;
        Mb[mi] = m_st;
        Lb[mi] = l_st;
    }
}

// ---------------------------------------------------------------------------
// Combine NS partials: O = sum_s w_s*O_s / sum_s w_s*l_s, w_s = exp2(m_s-m*).
// One thread per 4 d-columns of one q-row.
// ---------------------------------------------------------------------------
__global__ __launch_bounds__(256) void combine(const h16* __restrict__ OP,
                                               const float* __restrict__ Mb,
                                               const float* __restrict__ Lb,
                                               h16* __restrict__ AOh) {
    const int i  = blockIdx.x * 256 + threadIdx.x;   // 1M threads
    const int q  = i >> 8;
    const int c4 = (i & 255) * 4;
    const int hh = c4 >> 6;

    float ms[NS], ls[NS];
    float mstar = -1e30f;
    #pragma unroll
    for (int s = 0; s < NS; ++s) {
        const size_t mi = ((size_t)s * NH + hh) * SEQ + q;
        ms[s] = Mb[mi];
        ls[s] = Lb[mi];
        mstar = fmaxf(mstar, ms[s]);
    }
    float L = 0.0f;
    float acc[4] = {};
    #pragma unroll
    for (int s = 0; s < NS; ++s) {
        const float ws = exp2f(ms[s] - mstar);
        L += ls[s] * ws;
        const h16x4 ov = *(const h16x4*)(OP + (size_t)s * SEQ * DM + (size_t)q * DM + c4);
        acc[0] += ws * (float)ov[0];
        acc[1] += ws * (float)ov[1];
        acc[2] += ws * (float)ov[2];
        acc[3] += ws * (float)ov[3];
    }
    const float inv = 1.0f / L;
    h16x4 r = { (h16)(acc[0] * inv), (h16)(acc[1] * inv),
                (h16)(acc[2] * inv), (h16)(acc[3] * inv) };
    *(h16x4*)(AOh + (size_t)q * DM + c4) = r;
}

// ---------------------------------------------------------------------------
extern "C" void kernel_launch(void* const* d_in, const int* in_sizes, int n_in,
                              void* d_out, int out_size, void* d_ws, size_t ws_size,
                              hipStream_t stream) {
    const float* x  = (const float*)d_in[0];
    const float* Wq = (const float*)d_in[1];
    const float* Wk = (const float*)d_in[2];
    const float* Wv = (const float*)d_in[3];
    const float* Wo = (const float*)d_in[4];
    float* out = (float*)d_out;

    const size_t SD = (size_t)SEQ * DM;   // 4M
    const size_t DD = (size_t)DM * DM;    // 1M

    h16* xh  = (h16*)d_ws;                // cvt_all relies on this contiguity
    h16* wqh = xh + SD;
    h16* wkh = wqh + DD;
    h16* wvh = wkh + DD;
    h16* woh = wvh + DD;
    h16* Qh  = woh + DD;
    h16* Kh  = Qh + SD;
    h16* Vth = Kh + SD;                   // transposed: [DM][SEQ]
    h16* AOh = Vth + SD;
    h16* OP  = AOh + SD;                  // NS partial O buffers
    float* Mb = (float*)(OP + (size_t)NS * SD);
    float* Lb = Mb + (size_t)NS * NH * SEQ;

    const dim3 blk(256);

    cvt_all<<<(int)((SD + 4 * DD) / 4 / 256), blk, 0, stream>>>(x, Wq, Wk, Wv, Wo, xh);

    // Q pre-scaled by 1/sqrt(DH) * log2(e) for the exp2-domain softmax
    const float SCL = 0.125f * 1.44269504088896340736f;

    gemm_qkv<<<dim3(DM / 128, SEQ / 128, 3), blk, 0, stream>>>(
        xh, wqh, wkh, wvh, Qh, Kh, Vth, SCL);

    flash_attn_split<<<dim3(NH, 64, NS), blk, 0, stream>>>(Qh, Kh, Vth, OP, Mb, Lb);

    combine<<<(int)(SD / 4 / 256), blk, 0, stream>>>(OP, Mb, Lb, AOh);

    gemm_out<<<dim3(DM / 128, SEQ / 64), blk, 0, stream>>>(AOh, woh, out);
}